// Round 6
// baseline (301.740 us; speedup 1.0000x reference)
//
#include <hip/hip_runtime.h>
#include <hip/hip_bf16.h>

// MHA flash-attention fwd, fp32 in/out, f16 MFMA internals, fp32 accum.
// B=4, S=1024, D=2048, H=16, hd=128, causal.
// R12: SPLIT-K via TWO KERNELS (no atomics / no semaphore / no memset —
//      removes every nonstandard harness interaction R11 carried, after a
//      second "container failed" verdict gave no counters).
//      Evidence (R7-R10): latency-bound, ~2 effective streams/CU, wall =
//      per-CU-iters x ~5.35k cyc at 2-way overlap. Split qt>=8 chains into
//      2 k-halves: longest chain 16->8 iters AND 1536 blocks -> ~5 resident
//      + 1 queued per CU (2.5x streams). Static-max softmax => partials
//      combine linearly: kernel 2 does O = (n0+n1)/(d0+d1) (~50MB, ~10us).
//      Kernel boundary = all ordering. Fallback to R7 grid if ws too small.
//      Inner loop = R7 exactly (32KB LDS, 2-barrier, XOR swizzles, S^T
//      trick, prefetch-1-tile, pack deferred past barrier).

#define HEADS  16
#define HD     128
#define SEQ    1024
#define DMODEL 2048

typedef _Float16 f16;
typedef __attribute__((ext_vector_type(8))) _Float16 f16x8;
typedef __attribute__((ext_vector_type(4))) _Float16 f16x4;
typedef __attribute__((ext_vector_type(4))) float    f32x4;
typedef __attribute__((ext_vector_type(4))) unsigned int u32x4;

// ws layout: per pair (pair = bh*8 + (qt-8), 512 pairs) 16512 floats:
//   n0: +0 (64 rows x 128), n1: +8192, d0: +16384 (64), d1: +16448 (64)
#define WS_PAIR_FLOATS 16512
#define WS_NEEDED (512ull * WS_PAIR_FLOATS * 4ull)

__device__ __forceinline__ unsigned int pkrtz(float a, float b) {
    return __builtin_bit_cast(unsigned int, __builtin_amdgcn_cvt_pkrtz(a, b));
}

__global__ __launch_bounds__(256, 4)
void fa_fwd(const float* __restrict__ Q,
            const float* __restrict__ K,
            const float* __restrict__ V,
            float* __restrict__ O,
            float* __restrict__ WS)
{
    __shared__ f16 kT[64 * 128];   // K tile [key][d], 16B-granule swizzle g^(key&15)
    __shared__ f16 vT[128 * 64];   // V^T  [d][key], 16B-granule swizzle g^(d&7)

    const int tid  = threadIdx.x;
    const int lane = tid & 63;
    const int wv   = tid >> 6;
    const int quad = lane >> 4;
    const int cl   = lane & 15;

    const int bh = blockIdx.x;            // head; linear id % 8 == bh % 8 -> XCD-local
    const int yy = blockIdx.y;

    // ---- decode (qt, k-range, split) ----
    int qt, kt0, kt1, split, nsplit;
    if (gridDim.y == 16) {                // fallback: R7 grid, no splitting
        qt = 15 - yy; kt0 = 0; kt1 = qt + 1; split = 0; nsplit = 1;
    } else if (yy < 16) {                 // split halves of qt 15..8 (longest first)
        qt = 15 - (yy >> 1); split = yy & 1; nsplit = 2;
        const int h = (qt + 1) >> 1;
        kt0 = split ? h : 0;
        kt1 = split ? qt + 1 : h;
    } else {                              // qt 7..0, unsplit
        qt = 23 - yy; kt0 = 0; kt1 = qt + 1; split = 0; nsplit = 1;
    }
    const int qb = qt * 64;

    const long long head_off = ((long long)(bh >> 4) * SEQ) * DMODEL
                             + (long long)(bh & 15) * HD;
    const float rscale = 0.08838834764831845f;   // 1/sqrt(128)

    // K staging geometry: thread covers rows krow+16i, granule kg (8 f16)
    const int krow = tid >> 4;
    const int kg   = tid & 15;
    const int kgs  = kg ^ krow;           // swizzled granule ((krow+16i)&15 == krow)
    // V staging geometry: thread covers keys vr0,vr0+1 x d = vcg*16+j
    const int vr0  = (tid & 31) * 2;
    const int vcg  = tid >> 5;
    const int vg   = vr0 >> 3;            // key-granule
    const int vo   = vr0 & 7;             // within-granule key offset (even)

    f32x4 kraw[8], vraw[8];

    auto loadKV = [&](int kbase) {
        #pragma unroll
        for (int i = 0; i < 4; ++i) {
            const float* kp = K + head_off + (long long)(kbase + krow + i * 16) * DMODEL + kg * 8;
            kraw[2 * i]     = *(const f32x4*)kp;
            kraw[2 * i + 1] = *(const f32x4*)(kp + 4);
        }
        const float* vp = V + head_off + (long long)(kbase + vr0) * DMODEL + vcg * 16;
        #pragma unroll
        for (int j = 0; j < 4; ++j) {
            vraw[j]     = *(const f32x4*)(vp + 4 * j);
            vraw[4 + j] = *(const f32x4*)(vp + DMODEL + 4 * j);
        }
    };

    // ---- Q fragments (row = qb + wv*16 + cl, k = quad*8 + j per kk) ----
    const int qrow = qb + wv * 16 + cl;
    f16x8 qf[4];
    {
        const float* qp = Q + head_off + (long long)qrow * DMODEL + quad * 8;
        #pragma unroll
        for (int kk = 0; kk < 4; ++kk) {
            f32x4 qa = *(const f32x4*)(qp + kk * 32);
            f32x4 qc = *(const f32x4*)(qp + kk * 32 + 4);
            union { f16x8 v; unsigned int u[4]; } qw;
            qw.u[0] = pkrtz(qa[0], qa[1]);
            qw.u[1] = pkrtz(qa[2], qa[3]);
            qw.u[2] = pkrtz(qc[0], qc[1]);
            qw.u[3] = pkrtz(qc[2], qc[3]);
            qf[kk] = qw.v;
        }
    }

    f32x4 acc[8];    // O^T: row d = dt*16 + quad*4 + r, col qrow = cl
    #pragma unroll
    for (int i = 0; i < 8; ++i) acc[i] = (f32x4){0.f, 0.f, 0.f, 0.f};
    float ls = 0.f;

    loadKV(kt0 * 64);

    #pragma unroll 1
    for (int kt = kt0; kt < kt1; ++kt) {
        __syncthreads();   // prior iter's LDS reads complete

        // ---- pack (loads issued an iteration ago; vmcnt wait ~free) + stage ----
        #pragma unroll
        for (int i = 0; i < 4; ++i) {
            u32x4 w;
            w.x = pkrtz(kraw[2 * i][0], kraw[2 * i][1]);
            w.y = pkrtz(kraw[2 * i][2], kraw[2 * i][3]);
            w.z = pkrtz(kraw[2 * i + 1][0], kraw[2 * i + 1][1]);
            w.w = pkrtz(kraw[2 * i + 1][2], kraw[2 * i + 1][3]);
            *(u32x4*)&kT[(krow + 16 * i) * 128 + kgs * 8] = w;
        }
        #pragma unroll
        for (int j = 0; j < 16; ++j) {
            unsigned int pk = pkrtz(vraw[j >> 2][j & 3], vraw[4 + (j >> 2)][j & 3]);
            *(unsigned int*)&vT[(vcg * 16 + j) * 64 + ((vg ^ (j & 7)) * 8) + vo] = pk;
        }
        __syncthreads();

        if (kt < kt1 - 1) loadKV((kt + 1) * 64);   // in flight across GEMM1+exp+GEMM2+barrier

        // ---- S^T = K Q^T : C[key = st*16+quad*4+r][qrow = cl] ----
        f32x4 sc[4];
        #pragma unroll
        for (int st = 0; st < 4; ++st) sc[st] = (f32x4){0.f, 0.f, 0.f, 0.f};
        #pragma unroll
        for (int kk = 0; kk < 4; ++kk) {
            #pragma unroll
            for (int st = 0; st < 4; ++st) {
                f16x8 kf = *(const f16x8*)&kT[(st * 16 + cl) * 128
                                              + ((kk * 4 + quad) ^ cl) * 8];
                sc[st] = __builtin_amdgcn_mfma_f32_16x16x32_f16(kf, qf[kk], sc[st], 0, 0, 0);
            }
        }

        // ---- exp (static-max softmax) -> P^T directly in B-frag layout ----
        const int kbase = kt * 64;
        f16x4 pf[4];
        if (kt == qt) {                // diagonal tile: causal mask
            #pragma unroll
            for (int st = 0; st < 4; ++st) {
                float e[4];
                #pragma unroll
                for (int r = 0; r < 4; ++r) {
                    int key = kbase + st * 16 + quad * 4 + r;
                    float ex = __expf(sc[st][r] * rscale);
                    e[r] = (key <= qrow) ? ex : 0.f;
                    ls += e[r];
                }
                union { f16x4 v; unsigned int u[2]; } pw;
                pw.u[0] = pkrtz(e[0], e[1]);
                pw.u[1] = pkrtz(e[2], e[3]);
                pf[st] = pw.v;
            }
        } else {
            #pragma unroll
            for (int st = 0; st < 4; ++st) {
                float e[4];
                #pragma unroll
                for (int r = 0; r < 4; ++r) {
                    e[r] = __expf(sc[st][r] * rscale);
                    ls += e[r];
                }
                union { f16x4 v; unsigned int u[2]; } pw;
                pw.u[0] = pkrtz(e[0], e[1]);
                pw.u[1] = pkrtz(e[2], e[3]);
                pf[st] = pw.v;
            }
        }

        // ---- O^T += V^T P^T (x32 MFMAs; A = V^T from LDS, B = P^T in regs) ----
        #pragma unroll
        for (int dt = 0; dt < 8; ++dt) {
            #pragma unroll
            for (int st = 0; st < 4; ++st) {
                f16x4 vf = *(const f16x4*)&vT[(dt * 16 + cl) * 64
                                              + ((st * 2 + (quad >> 1)) ^ (cl & 7)) * 8
                                              + (quad & 1) * 4];
                acc[dt] = __builtin_amdgcn_mfma_f32_16x16x16f16(vf, pf[st], acc[dt], 0, 0, 0);
            }
        }
    }

    // ---- denominator reduce over quads (all lanes end with row total) ----
    float lsum = ls;
    lsum += __shfl_xor(lsum, 16, 64);
    lsum += __shfl_xor(lsum, 32, 64);

    if (nsplit == 1) {
        // ---- direct epilogue: normalize, store f32x4 ----
        const float rl = 1.0f / lsum;
        float* op = O + head_off + (long long)qrow * DMODEL + quad * 4;
        #pragma unroll
        for (int dt = 0; dt < 8; ++dt) {
            f32x4 o4 = acc[dt];
            o4[0] *= rl; o4[1] *= rl; o4[2] *= rl; o4[3] *= rl;
            *(f32x4*)(op + dt * 16) = o4;
        }
        return;
    }

    // ---- split epilogue: plain-store partial; merge kernel combines ----
    const int pairIdx = bh * 8 + (qt - 8);
    float* base  = WS + (long long)pairIdx * WS_PAIR_FLOATS;
    float* myNum = base + split * 8192;
    float* myDen = base + 16384 + split * 64;
    const int rloc = wv * 16 + cl;        // local row 0..63

    float* np = myNum + rloc * 128 + quad * 4;
    #pragma unroll
    for (int dt = 0; dt < 8; ++dt) {
        *(f32x4*)(np + dt * 16) = acc[dt];
    }
    if (quad == 0) myDen[rloc] = lsum;
}

// O = (n0 + n1) / (d0 + d1) for the 512 split pairs.
// grid 4096 x 256: bid = pair*8 + sub; i = sub*256+tid indexes f32x4 within pair.
__global__ __launch_bounds__(256, 8)
void fa_merge(const float* __restrict__ WS, float* __restrict__ O)
{
    const int bid  = blockIdx.x;
    const int pair = bid >> 3;
    const int sub  = bid & 7;
    const int bh   = pair >> 3;
    const int qt   = (pair & 7) + 8;
    const long long head_off = ((long long)(bh >> 4) * SEQ) * DMODEL
                             + (long long)(bh & 15) * HD;
    const float* base = WS + (long long)pair * WS_PAIR_FLOATS;

    const int i   = sub * 256 + threadIdx.x;   // f32x4 index in [0,2048)
    const int row = i >> 5;                    // 32 f32x4 per 128-wide row
    const int c4  = i & 31;

    const float d0 = base[16384 + row];
    const float d1 = base[16448 + row];
    const float rl = 1.0f / (d0 + d1);

    const f32x4 n0 = *(const f32x4*)(base + row * 128 + c4 * 4);
    const f32x4 n1 = *(const f32x4*)(base + 8192 + row * 128 + c4 * 4);
    f32x4 o;
    o[0] = (n0[0] + n1[0]) * rl;
    o[1] = (n0[1] + n1[1]) * rl;
    o[2] = (n0[2] + n1[2]) * rl;
    o[3] = (n0[3] + n1[3]) * rl;

    *(f32x4*)(O + head_off + (long long)(qt * 64 + row) * DMODEL + c4 * 4) = o;
}

extern "C" void kernel_launch(void* const* d_in, const int* in_sizes, int n_in,
                              void* d_out, int out_size, void* d_ws, size_t ws_size,
                              hipStream_t stream) {
    const float* q = (const float*)d_in[0];
    const float* k = (const float*)d_in[1];
    const float* v = (const float*)d_in[2];
    float* o = (float*)d_out;

    const bool do_split = (d_ws != nullptr) && (ws_size >= WS_NEEDED);
    if (do_split) {
        dim3 grid(4 * HEADS, 24);   // y 0..15: split halves qt 15..8; y 16..23: qt 7..0
        fa_fwd<<<grid, dim3(256), 0, stream>>>(q, k, v, o, (float*)d_ws);
        fa_merge<<<dim3(4096), dim3(256), 0, stream>>>((const float*)d_ws, o);
    } else {
        dim3 grid(4 * HEADS, 16);   // fallback: R7 grid
        fa_fwd<<<grid, dim3(256), 0, stream>>>(q, k, v, o, (float*)d_ws);
    }
}

// Round 7
// 183.964 us; speedup vs baseline: 1.6402x; 1.6402x over previous
//
#include <hip/hip_runtime.h>
#include <hip/hip_bf16.h>

// MHA flash-attention fwd, fp32 in/out, f16 MFMA internals, fp32 accum.
// B=4, S=1024, D=2048, H=16, hd=128, causal.
// R13: R12 with ONE fix: __launch_bounds__(256,2) restored on fa_fwd.
//      R12's (256,4) capped VGPRs at 64 -> catastrophic scratch spills
//      (FETCH 296MB, WRITE 311MB, 202us, MfmaUtil 5%). The split-K
//      experiment itself was never tested. Calibration from R12: merge
//      kernel costs only ~5-10us (harness overhead is ~93us fixed).
//      Structure: split qt>=8 causal chains into 2 k-halves -> longest
//      chain 16->8 iters, 1536 blocks (~5 resident/CU). Static-max
//      softmax => partials combine linearly; kernel 2 does
//      O = (n0+n1)/(d0+d1). Kernel boundary = all ordering (no atomics).
//      Inner loop = R7 exactly (32KB LDS, 2-barrier, XOR swizzles, S^T
//      trick, prefetch-1-tile, pack deferred past barrier).

#define HEADS  16
#define HD     128
#define SEQ    1024
#define DMODEL 2048

typedef _Float16 f16;
typedef __attribute__((ext_vector_type(8))) _Float16 f16x8;
typedef __attribute__((ext_vector_type(4))) _Float16 f16x4;
typedef __attribute__((ext_vector_type(4))) float    f32x4;
typedef __attribute__((ext_vector_type(4))) unsigned int u32x4;

// ws layout: per pair (pair = bh*8 + (qt-8), 512 pairs) 16512 floats:
//   n0: +0 (64 rows x 128), n1: +8192, d0: +16384 (64), d1: +16448 (64)
#define WS_PAIR_FLOATS 16512
#define WS_NEEDED (512ull * WS_PAIR_FLOATS * 4ull)

__device__ __forceinline__ unsigned int pkrtz(float a, float b) {
    return __builtin_bit_cast(unsigned int, __builtin_amdgcn_cvt_pkrtz(a, b));
}

__global__ __launch_bounds__(256, 2)
void fa_fwd(const float* __restrict__ Q,
            const float* __restrict__ K,
            const float* __restrict__ V,
            float* __restrict__ O,
            float* __restrict__ WS)
{
    __shared__ f16 kT[64 * 128];   // K tile [key][d], 16B-granule swizzle g^(key&15)
    __shared__ f16 vT[128 * 64];   // V^T  [d][key], 16B-granule swizzle g^(d&7)

    const int tid  = threadIdx.x;
    const int lane = tid & 63;
    const int wv   = tid >> 6;
    const int quad = lane >> 4;
    const int cl   = lane & 15;

    const int bh = blockIdx.x;            // head; linear id % 8 == bh % 8 -> XCD-local
    const int yy = blockIdx.y;

    // ---- decode (qt, k-range, split) ----
    int qt, kt0, kt1, split, nsplit;
    if (gridDim.y == 16) {                // fallback: R7 grid, no splitting
        qt = 15 - yy; kt0 = 0; kt1 = qt + 1; split = 0; nsplit = 1;
    } else if (yy < 16) {                 // split halves of qt 15..8 (longest first)
        qt = 15 - (yy >> 1); split = yy & 1; nsplit = 2;
        const int h = (qt + 1) >> 1;
        kt0 = split ? h : 0;
        kt1 = split ? qt + 1 : h;
    } else {                              // qt 7..0, unsplit
        qt = 23 - yy; kt0 = 0; kt1 = qt + 1; split = 0; nsplit = 1;
    }
    const int qb = qt * 64;

    const long long head_off = ((long long)(bh >> 4) * SEQ) * DMODEL
                             + (long long)(bh & 15) * HD;
    const float rscale = 0.08838834764831845f;   // 1/sqrt(128)

    // K staging geometry: thread covers rows krow+16i, granule kg (8 f16)
    const int krow = tid >> 4;
    const int kg   = tid & 15;
    const int kgs  = kg ^ krow;           // swizzled granule ((krow+16i)&15 == krow)
    // V staging geometry: thread covers keys vr0,vr0+1 x d = vcg*16+j
    const int vr0  = (tid & 31) * 2;
    const int vcg  = tid >> 5;
    const int vg   = vr0 >> 3;            // key-granule
    const int vo   = vr0 & 7;             // within-granule key offset (even)

    f32x4 kraw[8], vraw[8];

    auto loadKV = [&](int kbase) {
        #pragma unroll
        for (int i = 0; i < 4; ++i) {
            const float* kp = K + head_off + (long long)(kbase + krow + i * 16) * DMODEL + kg * 8;
            kraw[2 * i]     = *(const f32x4*)kp;
            kraw[2 * i + 1] = *(const f32x4*)(kp + 4);
        }
        const float* vp = V + head_off + (long long)(kbase + vr0) * DMODEL + vcg * 16;
        #pragma unroll
        for (int j = 0; j < 4; ++j) {
            vraw[j]     = *(const f32x4*)(vp + 4 * j);
            vraw[4 + j] = *(const f32x4*)(vp + DMODEL + 4 * j);
        }
    };

    // ---- Q fragments (row = qb + wv*16 + cl, k = quad*8 + j per kk) ----
    const int qrow = qb + wv * 16 + cl;
    f16x8 qf[4];
    {
        const float* qp = Q + head_off + (long long)qrow * DMODEL + quad * 8;
        #pragma unroll
        for (int kk = 0; kk < 4; ++kk) {
            f32x4 qa = *(const f32x4*)(qp + kk * 32);
            f32x4 qc = *(const f32x4*)(qp + kk * 32 + 4);
            union { f16x8 v; unsigned int u[4]; } qw;
            qw.u[0] = pkrtz(qa[0], qa[1]);
            qw.u[1] = pkrtz(qa[2], qa[3]);
            qw.u[2] = pkrtz(qc[0], qc[1]);
            qw.u[3] = pkrtz(qc[2], qc[3]);
            qf[kk] = qw.v;
        }
    }

    f32x4 acc[8];    // O^T: row d = dt*16 + quad*4 + r, col qrow = cl
    #pragma unroll
    for (int i = 0; i < 8; ++i) acc[i] = (f32x4){0.f, 0.f, 0.f, 0.f};
    float ls = 0.f;

    loadKV(kt0 * 64);

    #pragma unroll 1
    for (int kt = kt0; kt < kt1; ++kt) {
        __syncthreads();   // prior iter's LDS reads complete

        // ---- pack (loads issued an iteration ago; vmcnt wait ~free) + stage ----
        #pragma unroll
        for (int i = 0; i < 4; ++i) {
            u32x4 w;
            w.x = pkrtz(kraw[2 * i][0], kraw[2 * i][1]);
            w.y = pkrtz(kraw[2 * i][2], kraw[2 * i][3]);
            w.z = pkrtz(kraw[2 * i + 1][0], kraw[2 * i + 1][1]);
            w.w = pkrtz(kraw[2 * i + 1][2], kraw[2 * i + 1][3]);
            *(u32x4*)&kT[(krow + 16 * i) * 128 + kgs * 8] = w;
        }
        #pragma unroll
        for (int j = 0; j < 16; ++j) {
            unsigned int pk = pkrtz(vraw[j >> 2][j & 3], vraw[4 + (j >> 2)][j & 3]);
            *(unsigned int*)&vT[(vcg * 16 + j) * 64 + ((vg ^ (j & 7)) * 8) + vo] = pk;
        }
        __syncthreads();

        if (kt < kt1 - 1) loadKV((kt + 1) * 64);   // in flight across GEMM1+exp+GEMM2+barrier

        // ---- S^T = K Q^T : C[key = st*16+quad*4+r][qrow = cl] ----
        f32x4 sc[4];
        #pragma unroll
        for (int st = 0; st < 4; ++st) sc[st] = (f32x4){0.f, 0.f, 0.f, 0.f};
        #pragma unroll
        for (int kk = 0; kk < 4; ++kk) {
            #pragma unroll
            for (int st = 0; st < 4; ++st) {
                f16x8 kf = *(const f16x8*)&kT[(st * 16 + cl) * 128
                                              + ((kk * 4 + quad) ^ cl) * 8];
                sc[st] = __builtin_amdgcn_mfma_f32_16x16x32_f16(kf, qf[kk], sc[st], 0, 0, 0);
            }
        }

        // ---- exp (static-max softmax) -> P^T directly in B-frag layout ----
        const int kbase = kt * 64;
        f16x4 pf[4];
        if (kt == qt) {                // diagonal tile: causal mask
            #pragma unroll
            for (int st = 0; st < 4; ++st) {
                float e[4];
                #pragma unroll
                for (int r = 0; r < 4; ++r) {
                    int key = kbase + st * 16 + quad * 4 + r;
                    float ex = __expf(sc[st][r] * rscale);
                    e[r] = (key <= qrow) ? ex : 0.f;
                    ls += e[r];
                }
                union { f16x4 v; unsigned int u[2]; } pw;
                pw.u[0] = pkrtz(e[0], e[1]);
                pw.u[1] = pkrtz(e[2], e[3]);
                pf[st] = pw.v;
            }
        } else {
            #pragma unroll
            for (int st = 0; st < 4; ++st) {
                float e[4];
                #pragma unroll
                for (int r = 0; r < 4; ++r) {
                    e[r] = __expf(sc[st][r] * rscale);
                    ls += e[r];
                }
                union { f16x4 v; unsigned int u[2]; } pw;
                pw.u[0] = pkrtz(e[0], e[1]);
                pw.u[1] = pkrtz(e[2], e[3]);
                pf[st] = pw.v;
            }
        }

        // ---- O^T += V^T P^T (x32 MFMAs; A = V^T from LDS, B = P^T in regs) ----
        #pragma unroll
        for (int dt = 0; dt < 8; ++dt) {
            #pragma unroll
            for (int st = 0; st < 4; ++st) {
                f16x4 vf = *(const f16x4*)&vT[(dt * 16 + cl) * 64
                                              + ((st * 2 + (quad >> 1)) ^ (cl & 7)) * 8
                                              + (quad & 1) * 4];
                acc[dt] = __builtin_amdgcn_mfma_f32_16x16x16f16(vf, pf[st], acc[dt], 0, 0, 0);
            }
        }
    }

    // ---- denominator reduce over quads (all lanes end with row total) ----
    float lsum = ls;
    lsum += __shfl_xor(lsum, 16, 64);
    lsum += __shfl_xor(lsum, 32, 64);

    if (nsplit == 1) {
        // ---- direct epilogue: normalize, store f32x4 ----
        const float rl = 1.0f / lsum;
        float* op = O + head_off + (long long)qrow * DMODEL + quad * 4;
        #pragma unroll
        for (int dt = 0; dt < 8; ++dt) {
            f32x4 o4 = acc[dt];
            o4[0] *= rl; o4[1] *= rl; o4[2] *= rl; o4[3] *= rl;
            *(f32x4*)(op + dt * 16) = o4;
        }
        return;
    }

    // ---- split epilogue: plain-store partial; merge kernel combines ----
    const int pairIdx = bh * 8 + (qt - 8);
    float* base  = WS + (long long)pairIdx * WS_PAIR_FLOATS;
    float* myNum = base + split * 8192;
    float* myDen = base + 16384 + split * 64;
    const int rloc = wv * 16 + cl;        // local row 0..63

    float* np = myNum + rloc * 128 + quad * 4;
    #pragma unroll
    for (int dt = 0; dt < 8; ++dt) {
        *(f32x4*)(np + dt * 16) = acc[dt];
    }
    if (quad == 0) myDen[rloc] = lsum;
}

// O = (n0 + n1) / (d0 + d1) for the 512 split pairs.
// grid 4096 x 256: bid = pair*8 + sub; i = sub*256+tid indexes f32x4 within pair.
__global__ __launch_bounds__(256, 8)
void fa_merge(const float* __restrict__ WS, float* __restrict__ O)
{
    const int bid  = blockIdx.x;
    const int pair = bid >> 3;
    const int sub  = bid & 7;
    const int bh   = pair >> 3;
    const int qt   = (pair & 7) + 8;
    const long long head_off = ((long long)(bh >> 4) * SEQ) * DMODEL
                             + (long long)(bh & 15) * HD;
    const float* base = WS + (long long)pair * WS_PAIR_FLOATS;

    const int i   = sub * 256 + threadIdx.x;   // f32x4 index in [0,2048)
    const int row = i >> 5;                    // 32 f32x4 per 128-wide row
    const int c4  = i & 31;

    const float d0 = base[16384 + row];
    const float d1 = base[16448 + row];
    const float rl = 1.0f / (d0 + d1);

    const f32x4 n0 = *(const f32x4*)(base + row * 128 + c4 * 4);
    const f32x4 n1 = *(const f32x4*)(base + 8192 + row * 128 + c4 * 4);
    f32x4 o;
    o[0] = (n0[0] + n1[0]) * rl;
    o[1] = (n0[1] + n1[1]) * rl;
    o[2] = (n0[2] + n1[2]) * rl;
    o[3] = (n0[3] + n1[3]) * rl;

    *(f32x4*)(O + head_off + (long long)(qt * 64 + row) * DMODEL + c4 * 4) = o;
}

extern "C" void kernel_launch(void* const* d_in, const int* in_sizes, int n_in,
                              void* d_out, int out_size, void* d_ws, size_t ws_size,
                              hipStream_t stream) {
    const float* q = (const float*)d_in[0];
    const float* k = (const float*)d_in[1];
    const float* v = (const float*)d_in[2];
    float* o = (float*)d_out;

    const bool do_split = (d_ws != nullptr) && (ws_size >= WS_NEEDED);
    if (do_split) {
        dim3 grid(4 * HEADS, 24);   // y 0..15: split halves qt 15..8; y 16..23: qt 7..0
        fa_fwd<<<grid, dim3(256), 0, stream>>>(q, k, v, o, (float*)d_ws);
        fa_merge<<<dim3(4096), dim3(256), 0, stream>>>((const float*)d_ws, o);
    } else {
        dim3 grid(4 * HEADS, 16);   // fallback: R7 grid
        fa_fwd<<<grid, dim3(256), 0, stream>>>(q, k, v, o, (float*)d_ws);
    }
}